// Round 10
// baseline (64.438 us; speedup 1.0000x reference)
//
#include <hip/hip_runtime.h>

#define T_STEPS 100
#define BATCH 256
#define NIN 784
#define N0 64
#define N1 64
#define N2 10
#define CHUNK (BATCH*N0 + BATCH*N1 + BATCH*N2)   // 35328
#define KPAD 800
#define WPLANE (N0*KPAD)                         // 51200 shorts per split plane
#define I0ELEMS (25600*64)

typedef __attribute__((ext_vector_type(8))) short short8;
typedef __attribute__((ext_vector_type(4))) float f32x4;

__device__ inline short bf16_rne(float x) {
  unsigned u = __float_as_uint(x);
  unsigned h = (u + 0x7FFFu + ((u >> 16) & 1u)) >> 16;
  return (short)h;
}
__device__ inline float bf16_val(short h) {
  return __uint_as_float(((unsigned)(unsigned short)h) << 16);
}

// ---------------------------------------------------------------------------
// Kernel 0: split W0 (f32 [64][784]) into 3 bf16 planes [64][800] (zero-pad).
// ---------------------------------------------------------------------------
__global__ __launch_bounds__(256) void prep_w0(
    const float* __restrict__ W0, short* __restrict__ W0s) {
  int idx = blockIdx.x * 256 + threadIdx.x;      // 0..51199
  int col = idx / KPAD, k = idx - col * KPAD;
  float w = (k < NIN) ? W0[col * NIN + k] : 0.0f;
  short h0 = bf16_rne(w);
  float r1 = w - bf16_val(h0);
  short h1 = bf16_rne(r1);
  float r2 = r1 - bf16_val(h1);
  short h2 = bf16_rne(r2);
  W0s[idx]              = h0;
  W0s[WPLANE + idx]     = h1;
  W0s[2 * WPLANE + idx] = h2;
}

// ---------------------------------------------------------------------------
// Kernel 1: I0T = X @ W0^T + b0 via bf16x3 MFMA, fragments direct from global.
// R9 structure; R10 changes: (a) launch_bounds(256,2) — R9's (256,3) forced
// VGPR=64 and serialized every load at full latency; (b) explicit pipeline:
// A-loads for chunk c+1 issued before chunk c's compute, B-loads batch-issued
// (12 concurrent) at chunk top. FP order identical to R8/R9.
// ---------------------------------------------------------------------------
__global__ __launch_bounds__(256, 2) void gemm0_kernel(
    const float* __restrict__ X, const short* __restrict__ W0s,
    const float* __restrict__ b0, float* __restrict__ I0T) {
  __shared__ float red[4][32][68];               // 34.8 KB wave-partials

  const int tid = threadIdx.x;
  const int r0  = blockIdx.x * 32;
  const int wid = tid >> 6;                      // wave 0..3 = k-split
  const int l   = tid & 63;
  const int lr  = l & 15;                        // frag row/col lane
  const int lk  = l >> 4;                        // frag k-octet lane

  const int kbeg = wid * 192;
  const int ccnt = (wid < 3) ? 6 : 7;            // last: 208 real k + 16 pad

  f32x4 acc[2][4];
#pragma unroll
  for (int rt = 0; rt < 2; ++rt)
#pragma unroll
    for (int ct = 0; ct < 4; ++ct) acc[rt][ct] = f32x4{0.f, 0.f, 0.f, 0.f};

  const float*  xr0 = X + (size_t)(r0 + lr) * NIN;
  const float*  xr1 = xr0 + 16 * NIN;
  const short8* wp  = (const short8*)W0s;        // 100 short8 per row

  // ---- prologue: A-load chunk 0
  float4 cxa0, cxb0, cxa1, cxb1;
  {
    const int k0 = kbeg + lk * 8;
    if (k0 < NIN) {
      cxa0 = *(const float4*)(xr0 + k0);
      cxb0 = *(const float4*)(xr0 + k0 + 4);
      cxa1 = *(const float4*)(xr1 + k0);
      cxb1 = *(const float4*)(xr1 + k0 + 4);
    } else {
      cxa0 = cxb0 = cxa1 = cxb1 = float4{0.f, 0.f, 0.f, 0.f};
    }
  }

  for (int c = 0; c < ccnt; ++c) {
    const int kb = kbeg + c * 32;
    const bool more = (c + 1 < ccnt);

    // ---- issue next chunk's A-loads (HBM latency hides under this chunk)
    float4 nxa0, nxb0, nxa1, nxb1;
    if (more) {
      const int k0n = kb + 32 + lk * 8;
      if (k0n < NIN) {
        nxa0 = *(const float4*)(xr0 + k0n);
        nxb0 = *(const float4*)(xr0 + k0n + 4);
        nxa1 = *(const float4*)(xr1 + k0n);
        nxb1 = *(const float4*)(xr1 + k0n + 4);
      } else {
        nxa0 = nxb0 = nxa1 = nxb1 = float4{0.f, 0.f, 0.f, 0.f};
      }
    }

    // ---- batch-issue this chunk's 12 B-loads (L2-resident, MLP)
    const int kof = kb / 8 + lk;
    short8 cb[4][3];
#pragma unroll
    for (int ct = 0; ct < 4; ++ct) {
      const size_t col = (size_t)(ct * 16 + lr);
      cb[ct][0] = wp[        col * 100 + kof];
      cb[ct][1] = wp[ 6400 + col * 100 + kof];
      cb[ct][2] = wp[12800 + col * 100 + kof];
    }

    // ---- convert this chunk's A to bf16x3 fragments (overlaps B latency)
    short8 a0[3], a1[3];
    {
      float xs0[8] = {cxa0.x, cxa0.y, cxa0.z, cxa0.w, cxb0.x, cxb0.y, cxb0.z, cxb0.w};
      float xs1[8] = {cxa1.x, cxa1.y, cxa1.z, cxa1.w, cxb1.x, cxb1.y, cxb1.z, cxb1.w};
#pragma unroll
      for (int e = 0; e < 8; ++e) {
        float x  = xs0[e];
        short h0 = bf16_rne(x);   float rr1 = x - bf16_val(h0);
        short h1 = bf16_rne(rr1); float rr2 = rr1 - bf16_val(h1);
        a0[0][e] = h0; a0[1][e] = h1; a0[2][e] = bf16_rne(rr2);
        x  = xs1[e];
        h0 = bf16_rne(x);   rr1 = x - bf16_val(h0);
        h1 = bf16_rne(rr1); rr2 = rr1 - bf16_val(h1);
        a1[0][e] = h0; a1[1][e] = h1; a1[2][e] = bf16_rne(rr2);
      }
    }

    // ---- MFMA: 2 row-tiles x 4 col-tiles x 6 products (R8 order)
#pragma unroll
    for (int ct = 0; ct < 4; ++ct) {
      {
        f32x4 a = acc[0][ct];
        a = __builtin_amdgcn_mfma_f32_16x16x32_bf16(a0[2], cb[ct][0], a, 0, 0, 0);
        a = __builtin_amdgcn_mfma_f32_16x16x32_bf16(a0[0], cb[ct][2], a, 0, 0, 0);
        a = __builtin_amdgcn_mfma_f32_16x16x32_bf16(a0[1], cb[ct][1], a, 0, 0, 0);
        a = __builtin_amdgcn_mfma_f32_16x16x32_bf16(a0[1], cb[ct][0], a, 0, 0, 0);
        a = __builtin_amdgcn_mfma_f32_16x16x32_bf16(a0[0], cb[ct][1], a, 0, 0, 0);
        a = __builtin_amdgcn_mfma_f32_16x16x32_bf16(a0[0], cb[ct][0], a, 0, 0, 0);
        acc[0][ct] = a;
      }
      {
        f32x4 a = acc[1][ct];
        a = __builtin_amdgcn_mfma_f32_16x16x32_bf16(a1[2], cb[ct][0], a, 0, 0, 0);
        a = __builtin_amdgcn_mfma_f32_16x16x32_bf16(a1[0], cb[ct][2], a, 0, 0, 0);
        a = __builtin_amdgcn_mfma_f32_16x16x32_bf16(a1[1], cb[ct][1], a, 0, 0, 0);
        a = __builtin_amdgcn_mfma_f32_16x16x32_bf16(a1[1], cb[ct][0], a, 0, 0, 0);
        a = __builtin_amdgcn_mfma_f32_16x16x32_bf16(a1[0], cb[ct][1], a, 0, 0, 0);
        a = __builtin_amdgcn_mfma_f32_16x16x32_bf16(a1[0], cb[ct][0], a, 0, 0, 0);
        acc[1][ct] = a;
      }
    }

    // ---- rotate prefetched A into current
    if (more) {
      cxa0 = nxa0; cxb0 = nxb0; cxa1 = nxa1; cxb1 = nxb1;
    }
  }

  // ---- epilogue: wave-partials -> LDS  (C/D: col=l&15, row=(l>>4)*4+r)
#pragma unroll
  for (int rt = 0; rt < 2; ++rt)
#pragma unroll
    for (int ct = 0; ct < 4; ++ct)
#pragma unroll
      for (int r = 0; r < 4; ++r)
        red[wid][rt * 16 + lk * 4 + r][ct * 16 + lr] = acc[rt][ct][r];
  __syncthreads();

  // ---- reduce 4 partials + bias (R8 order), write b-major I0T
  const int t0  = r0 >> 8;
  const int bb0 = r0 & 255;
  for (int idx = tid; idx < 32 * 16; idx += 256) {
    int row = idx >> 4, q = idx & 15;
    float4 v  = *(const float4*)&red[0][row][q * 4];
    float4 u1 = *(const float4*)&red[1][row][q * 4];
    float4 u2 = *(const float4*)&red[2][row][q * 4];
    float4 u3 = *(const float4*)&red[3][row][q * 4];
    v.x += u1.x; v.y += u1.y; v.z += u1.z; v.w += u1.w;
    v.x += u2.x; v.y += u2.y; v.z += u2.z; v.w += u2.w;
    v.x += u3.x; v.y += u3.y; v.z += u3.z; v.w += u3.w;
    float4 bv = ((const float4*)b0)[q];
    v.x += bv.x; v.y += bv.y; v.z += bv.z; v.w += bv.w;
    ((float4*)I0T)[((size_t)(bb0 + row) * T_STEPS + t0) * 16 + q] = v;
  }
}

// ---------------------------------------------------------------------------
// Kernel 2: one block per batch element (unchanged).
// ---------------------------------------------------------------------------
__global__ __launch_bounds__(256) void fused_kernel(
    const float* __restrict__ I0T,
    const float* __restrict__ W1, const float* __restrict__ b1,
    const float* __restrict__ W2, const float* __restrict__ b2,
    float* __restrict__ out) {
  __shared__ float bufA[112][68];
  __shared__ float sW1t[64][68];
  __shared__ float sW2[N2][68];
  __shared__ float sI2[T_STEPS][N2];

  const int b   = blockIdx.x;
  const int tid = threadIdx.x;
  const int j   = tid & 63;
  const int tq  = tid >> 6;
  float* outSpk = out;
  float* laySpk = out + T_STEPS * BATCH * N2;

  {
    const float4* src = (const float4*)I0T + (size_t)b * (T_STEPS * 16);
    for (int idx = tid; idx < T_STEPS * 16; idx += 256) {
      float4 v = src[idx];
      int t = idx >> 4, j4 = idx & 15;
      *(float4*)&bufA[t][j4 * 4] = v;
    }
  }
  __syncthreads();

  if (tq == 0) {
    float v = 0.0f;
#pragma unroll
    for (int g = 0; g < 4; ++g) {
      float ic[25];
#pragma unroll
      for (int i = 0; i < 25; ++i) ic[i] = bufA[g * 25 + i][j];
#pragma unroll
      for (int i = 0; i < 25; ++i) {
        v = v + 0.05f * ((0.0f - v) + ic[i]);
        float z = (v > 1.0f) ? 1.0f : 0.0f;
        v -= z;
        ic[i] = z;
      }
#pragma unroll
      for (int i = 0; i < 25; ++i) bufA[g * 25 + i][j] = ic[i];
    }
  } else {
    for (int idx = tid - 64; idx < 64 * 16; idx += 192) {
      int i = idx >> 4, jv = idx & 15;
      float4 wv = *(const float4*)(W1 + (size_t)i * 64 + jv * 4);
      sW1t[jv * 4 + 0][i] = wv.x;
      sW1t[jv * 4 + 1][i] = wv.y;
      sW1t[jv * 4 + 2][i] = wv.z;
      sW1t[jv * 4 + 3][i] = wv.w;
    }
    for (int idx = tid - 64; idx < N2 * 16; idx += 192) {
      int o = idx >> 4, jv = idx & 15;
      *(float4*)&sW2[o][jv * 4] = *(const float4*)(W2 + (size_t)o * 64 + jv * 4);
    }
  }
  __syncthreads();

  for (int idx = tid; idx < T_STEPS * 16; idx += 256) {
    int t = idx >> 4, jv = idx & 15;
    *(float4*)(laySpk + (size_t)t * CHUNK + b * 64 + jv * 4) =
        *(const float4*)&bufA[t][jv * 4];
  }

  const int iq = tid & 15;
  const int ts = tid >> 4;
  float g1[4][7];
  {
    float4 bias = *(const float4*)(b1 + iq * 4);
#pragma unroll
    for (int tt = 0; tt < 7; ++tt) {
      g1[0][tt] = bias.x; g1[1][tt] = bias.y; g1[2][tt] = bias.z; g1[3][tt] = bias.w;
    }
#pragma unroll
    for (int jq = 0; jq < 16; ++jq) {
      float4 z4[7];
#pragma unroll
      for (int tt = 0; tt < 7; ++tt)
        z4[tt] = *(const float4*)&bufA[ts * 7 + tt][jq * 4];
      float4 w4[4];
#pragma unroll
      for (int e = 0; e < 4; ++e)
        w4[e] = *(const float4*)&sW1t[jq * 4 + e][iq * 4];
#pragma unroll
      for (int e = 0; e < 4; ++e) {
#pragma unroll
        for (int tt = 0; tt < 7; ++tt) {
          float zv = ((const float*)&z4[tt])[e];
          g1[0][tt] = fmaf(zv, w4[e].x, g1[0][tt]);
          g1[1][tt] = fmaf(zv, w4[e].y, g1[1][tt]);
          g1[2][tt] = fmaf(zv, w4[e].z, g1[2][tt]);
          g1[3][tt] = fmaf(zv, w4[e].w, g1[3][tt]);
        }
      }
    }
  }
  __syncthreads();
#pragma unroll
  for (int tt = 0; tt < 7; ++tt) {
    float4 o = {g1[0][tt], g1[1][tt], g1[2][tt], g1[3][tt]};
    *(float4*)&bufA[ts * 7 + tt][iq * 4] = o;
  }
  __syncthreads();

  if (tq == 0) {
    float v = 0.0f;
#pragma unroll
    for (int g = 0; g < 4; ++g) {
      float ic[25];
#pragma unroll
      for (int i = 0; i < 25; ++i) ic[i] = bufA[g * 25 + i][j];
#pragma unroll
      for (int i = 0; i < 25; ++i) {
        v = v + 0.05f * ((0.0f - v) + ic[i]);
        float z = (v > 1.0f) ? 1.0f : 0.0f;
        v -= z;
        ic[i] = z;
      }
#pragma unroll
      for (int i = 0; i < 25; ++i) bufA[g * 25 + i][j] = ic[i];
    }
  }
  __syncthreads();

  for (int idx = tid; idx < T_STEPS * 16; idx += 256) {
    int t = idx >> 4, jv = idx & 15;
    *(float4*)(laySpk + (size_t)t * CHUNK + BATCH * N0 + b * 64 + jv * 4) =
        *(const float4*)&bufA[t][jv * 4];
  }

  for (int idx = tid; idx < T_STEPS * N2; idx += 256) {
    int t = idx / N2, o = idx % N2;
    float a = b2[o];
#pragma unroll
    for (int jq = 0; jq < 16; ++jq) {
      float4 z = *(const float4*)&bufA[t][jq * 4];
      float4 wv = *(const float4*)&sW2[o][jq * 4];
      a += z.x * wv.x;
      a += z.y * wv.y;
      a += z.z * wv.z;
      a += z.w * wv.w;
    }
    sI2[t][o] = a;
  }
  __syncthreads();

  if (tid < N2) {
    float v = 0.0f;
#pragma unroll
    for (int g = 0; g < 4; ++g) {
      float ic[25];
#pragma unroll
      for (int i = 0; i < 25; ++i) ic[i] = sI2[g * 25 + i][tid];
#pragma unroll
      for (int i = 0; i < 25; ++i) {
        v = v + 0.05f * ((0.0f - v) + ic[i]);
        float z = (v > 1.0f) ? 1.0f : 0.0f;
        v -= z;
        ic[i] = z;
      }
#pragma unroll
      for (int i = 0; i < 25; ++i) sI2[g * 25 + i][tid] = ic[i];
    }
  }
  __syncthreads();

  for (int idx = tid; idx < T_STEPS * N2; idx += 256) {
    int t = idx / N2, o = idx % N2;
    float z = sI2[t][o];
    outSpk[(size_t)t * (BATCH * N2) + b * N2 + o] = z;
    laySpk[(size_t)t * CHUNK + BATCH * (N0 + N1) + b * N2 + o] = z;
  }
}

extern "C" void kernel_launch(void* const* d_in, const int* in_sizes, int n_in,
                              void* d_out, int out_size, void* d_ws, size_t ws_size,
                              hipStream_t stream) {
  const float* inp = (const float*)d_in[0];
  const float* W0  = (const float*)d_in[1];
  const float* b0  = (const float*)d_in[2];
  const float* W1  = (const float*)d_in[3];
  const float* b1  = (const float*)d_in[4];
  const float* W2  = (const float*)d_in[5];
  const float* b2  = (const float*)d_in[6];

  float* I0T = (float*)d_ws;                 // 6.55 MB, b-major [b][t][j]
  short* W0s = (short*)(I0T + I0ELEMS);      // 3 x 100 KB bf16 splits

  prep_w0<<<dim3(200), dim3(256), 0, stream>>>(W0, W0s);
  gemm0_kernel<<<dim3(800), dim3(256), 0, stream>>>(inp, W0s, b0, I0T);
  fused_kernel<<<dim3(BATCH), dim3(256), 0, stream>>>(I0T, W1, b1, W2, b2,
                                                      (float*)d_out);
}